// Round 1
// baseline (299.685 us; speedup 1.0000x reference)
//
#include <hip/hip_runtime.h>
#include <math.h>

#define D_MODEL 1024
#define T_SEQ   2048
#define NBATCH  4

#define SKLD 264   // klds row stride (floats): 256 + 8, multiple of 4 -> 16B aligned, 2-way banks max
#define SQLD 20    // qlds row stride (floats)

// ---------- top-4 helpers: total order = (value desc, index asc) ----------
__device__ __forceinline__ bool key_gt(float av, int ai, float bv, int bi) {
    return (av > bv) || (av == bv && ai < bi);
}

__device__ __forceinline__ void cmpswap(float& v0, int& i0, float& v1, int& i1) {
    bool sw = key_gt(v1, i1, v0, i0);
    float nv0 = sw ? v1 : v0, nv1 = sw ? v0 : v1;
    int   ni0 = sw ? i1 : i0, ni1 = sw ? i0 : i1;
    v0 = nv0; v1 = nv1; i0 = ni0; i1 = ni1;
}

// merge sorted-desc a[4] with sorted-desc b[4] -> top4 of union into a (bitonic)
__device__ __forceinline__ void merge4(float (&a)[4], int (&ai)[4],
                                       float b0, int j0, float b1, int j1,
                                       float b2, int j2, float b3, int j3) {
    if (!key_gt(a[0], ai[0], b3, j3)) { a[0] = b3; ai[0] = j3; }
    if (!key_gt(a[1], ai[1], b2, j2)) { a[1] = b2; ai[1] = j2; }
    if (!key_gt(a[2], ai[2], b1, j1)) { a[2] = b1; ai[2] = j1; }
    if (!key_gt(a[3], ai[3], b0, j0)) { a[3] = b0; ai[3] = j0; }
    cmpswap(a[0], ai[0], a[2], ai[2]);
    cmpswap(a[1], ai[1], a[3], ai[3]);
    cmpswap(a[0], ai[0], a[1], ai[1]);
    cmpswap(a[2], ai[2], a[3], ai[3]);
}

// insert candidate (v, idx) into sorted-desc top4; strict > so ties keep earlier index
__device__ __forceinline__ void insert4(float (&tv)[4], int (&tix)[4], float v, int idx) {
    if (v > tv[3]) {
        bool g0 = v > tv[0], g1 = v > tv[1], g2 = v > tv[2];
        float n0 = g0 ? v : tv[0];
        int   m0 = g0 ? idx : tix[0];
        float n1 = g1 ? (g0 ? tv[0] : v) : tv[1];
        int   m1 = g1 ? (g0 ? tix[0] : idx) : tix[1];
        float n2 = g2 ? (g1 ? tv[1] : v) : tv[2];
        int   m2 = g2 ? (g1 ? tix[1] : idx) : tix[2];
        float n3 = g2 ? tv[2] : v;
        int   m3 = g2 ? tix[2] : idx;
        tv[0] = n0; tv[1] = n1; tv[2] = n2; tv[3] = n3;
        tix[0] = m0; tix[1] = m1; tix[2] = m2; tix[3] = m3;
    }
}

// ---------- Phase 1: Q = x Wq^T + bq, K = x Wk^T + bk (fp64 accumulate) ----------
// Outputs stored TRANSPOSED: Qt[b][o][t], Kt[b][o][t]  (o = 0..31)
// grid 512, block 256; 16 rows/block, thread = (o = tid&31, row pair = tid>>5)
__global__ __launch_bounds__(256) void proj_kernel(
    const float* __restrict__ x,
    const float* __restrict__ Wq, const float* __restrict__ bq,
    const float* __restrict__ Wk, const float* __restrict__ bk,
    float* __restrict__ Qt, float* __restrict__ Kt)
{
    const int o    = threadIdx.x & 31;
    const int rl   = threadIdx.x >> 5;
    const int row0 = blockIdx.x * 16 + rl * 2;

    const float4* xr0 = reinterpret_cast<const float4*>(x + (size_t)row0 * D_MODEL);
    const float4* xr1 = reinterpret_cast<const float4*>(x + ((size_t)row0 + 1) * D_MODEL);
    const float4* wq  = reinterpret_cast<const float4*>(Wq + (size_t)o * D_MODEL);
    const float4* wk  = reinterpret_cast<const float4*>(Wk + (size_t)o * D_MODEL);

    double aq0 = 0.0, ak0 = 0.0, aq1 = 0.0, ak1 = 0.0;
    #pragma unroll 4
    for (int i = 0; i < D_MODEL / 4; ++i) {
        float4 x0 = xr0[i], x1 = xr1[i];
        float4 q4 = wq[i],  k4 = wk[i];
        double xd0[4] = {x0.x, x0.y, x0.z, x0.w};
        double xd1[4] = {x1.x, x1.y, x1.z, x1.w};
        double qd[4]  = {q4.x, q4.y, q4.z, q4.w};
        double kd[4]  = {k4.x, k4.y, k4.z, k4.w};
        #pragma unroll
        for (int u = 0; u < 4; ++u) {
            aq0 = fma(xd0[u], qd[u], aq0);
            ak0 = fma(xd0[u], kd[u], ak0);
            aq1 = fma(xd1[u], qd[u], aq1);
            ak1 = fma(xd1[u], kd[u], ak1);
        }
    }
    const double bqd = (double)bq[o], bkd = (double)bk[o];
    {
        const int bb = row0 >> 11, t = row0 & 2047;
        Qt[((size_t)bb * 32 + o) * T_SEQ + t] = (float)(aq0 + bqd);
        Kt[((size_t)bb * 32 + o) * T_SEQ + t] = (float)(ak0 + bkd);
    }
    {
        const int r1 = row0 + 1;
        const int bb = r1 >> 11, t = r1 & 2047;
        Qt[((size_t)bb * 32 + o) * T_SEQ + t] = (float)(aq1 + bqd);
        Kt[((size_t)bb * 32 + o) * T_SEQ + t] = (float)(ak1 + bkd);
    }
}

// ---------- Phase 2: sim = Q K^T, per-row top-4, fused gather+mean ----------
// grid 512 (= 4 batches * 128 t-tiles of 16), block 256 (4 waves)
// thread micro-tile: 4 t-rows (t0 = (tid&3)*4) x 4 s-cols (s0 = (tid>>2)*4) per 256-s tile
__global__ __launch_bounds__(256) void topk_gather_kernel(
    const float* __restrict__ x, const float* __restrict__ Qt,
    const float* __restrict__ Kt, float* __restrict__ out)
{
    __shared__ float klds[32 * SKLD];     // K^T tile: [i][s], 33792 B
    __shared__ float qlds[32 * SQLD];     // Q^T tile: [i][t], 2560 B
    __shared__ float candV[4][16][4];
    __shared__ int   candI[4][16][4];
    __shared__ int   topIdx[16][4];

    const int tid  = threadIdx.x;
    const int lane = tid & 63;
    const int wav  = tid >> 6;
    const int b    = blockIdx.x >> 7;
    const int tblk = (blockIdx.x & 127) * 16;

    const float* QtB = Qt + (size_t)b * 32 * T_SEQ;
    const float* KtB = Kt + (size_t)b * 32 * T_SEQ;

    // stage Q^T tile: 32 i x 16 t
    if (tid < 128) {
        const int i  = tid >> 2;
        const int t4 = (tid & 3) * 4;
        float4 v = *reinterpret_cast<const float4*>(QtB + (size_t)i * T_SEQ + tblk + t4);
        *reinterpret_cast<float4*>(&qlds[i * SQLD + t4]) = v;
    }

    const int tg = tid & 3;
    const int t0 = tg * 4;
    const int s0 = (tid >> 2) * 4;

    float tv[4][4]; int tix[4][4];
    #pragma unroll
    for (int r = 0; r < 4; ++r)
        #pragma unroll
        for (int j = 0; j < 4; ++j) { tv[r][j] = -INFINITY; tix[r][j] = 0x7fffffff; }

    for (int st = 0; st < 8; ++st) {
        __syncthreads();  // prev tile consumed (also covers qlds at st==0)
        // stage K^T tile: 32 i x 256 s, coalesced float4, contiguous LDS rows
        #pragma unroll
        for (int j = 0; j < 8; ++j) {
            const int f  = (tid + j * 256) * 4;
            const int ki = f >> 8;
            const int ks = f & 255;
            float4 v = *reinterpret_cast<const float4*>(KtB + (size_t)ki * T_SEQ + st * 256 + ks);
            *reinterpret_cast<float4*>(&klds[ki * SKLD + ks]) = v;
        }
        __syncthreads();

        float acc[4][4];
        #pragma unroll
        for (int r = 0; r < 4; ++r)
            #pragma unroll
            for (int c = 0; c < 4; ++c) acc[r][c] = 0.f;

        #pragma unroll 8
        for (int i = 0; i < 32; ++i) {
            float4 qv = *reinterpret_cast<const float4*>(&qlds[i * SQLD + t0]);
            float4 kv = *reinterpret_cast<const float4*>(&klds[i * SKLD + s0]);
            const float qa[4] = {qv.x, qv.y, qv.z, qv.w};
            const float ka[4] = {kv.x, kv.y, kv.z, kv.w};
            #pragma unroll
            for (int r = 0; r < 4; ++r)
                #pragma unroll
                for (int c = 0; c < 4; ++c)
                    acc[r][c] = fmaf(qa[r], ka[c], acc[r][c]);
        }

        const int sbase = st * 256 + s0;
        #pragma unroll
        for (int c = 0; c < 4; ++c)
            #pragma unroll
            for (int r = 0; r < 4; ++r)
                insert4(tv[r], tix[r], acc[r][c], sbase + c);
    }

    // wave butterfly: lanes sharing (tid&3) hold the same 4 t-rows; masks preserve tid&3
    #pragma unroll
    for (int m = 4; m <= 32; m <<= 1) {
        #pragma unroll
        for (int r = 0; r < 4; ++r) {
            float b0 = __shfl_xor(tv[r][0], m, 64);
            float b1 = __shfl_xor(tv[r][1], m, 64);
            float b2 = __shfl_xor(tv[r][2], m, 64);
            float b3 = __shfl_xor(tv[r][3], m, 64);
            int   j0 = __shfl_xor(tix[r][0], m, 64);
            int   j1 = __shfl_xor(tix[r][1], m, 64);
            int   j2 = __shfl_xor(tix[r][2], m, 64);
            int   j3 = __shfl_xor(tix[r][3], m, 64);
            merge4(tv[r], tix[r], b0, j0, b1, j1, b2, j2, b3, j3);
        }
    }

    // one representative lane per t-group per wave
    if (lane < 4) {
        #pragma unroll
        for (int r = 0; r < 4; ++r)
            #pragma unroll
            for (int j = 0; j < 4; ++j) {
                candV[wav][lane * 4 + r][j] = tv[r][j];
                candI[wav][lane * 4 + r][j] = tix[r][j];
            }
    }
    __syncthreads();

    // cross-wave merge: thread t < 16 owns row t
    if (tid < 16) {
        float mv[4]; int mi[4];
        #pragma unroll
        for (int j = 0; j < 4; ++j) { mv[j] = candV[0][tid][j]; mi[j] = candI[0][tid][j]; }
        #pragma unroll
        for (int w = 1; w < 4; ++w)
            merge4(mv, mi,
                   candV[w][tid][0], candI[w][tid][0],
                   candV[w][tid][1], candI[w][tid][1],
                   candV[w][tid][2], candI[w][tid][2],
                   candV[w][tid][3], candI[w][tid][3]);
        #pragma unroll
        for (int j = 0; j < 4; ++j) topIdx[tid][j] = mi[j];
    }
    __syncthreads();

    // fused gather + mean: one float4 per thread per row, fully coalesced
    const float* xb = x + (size_t)b * T_SEQ * D_MODEL;
    float* ob = out + ((size_t)b * T_SEQ + tblk) * D_MODEL;
    for (int r = 0; r < 16; ++r) {
        const int i0 = topIdx[r][0], i1 = topIdx[r][1], i2 = topIdx[r][2], i3 = topIdx[r][3];
        float4 a0 = *(reinterpret_cast<const float4*>(xb + (size_t)i0 * D_MODEL) + tid);
        float4 a1 = *(reinterpret_cast<const float4*>(xb + (size_t)i1 * D_MODEL) + tid);
        float4 a2 = *(reinterpret_cast<const float4*>(xb + (size_t)i2 * D_MODEL) + tid);
        float4 a3 = *(reinterpret_cast<const float4*>(xb + (size_t)i3 * D_MODEL) + tid);
        float4 o;
        o.x = (a0.x + a1.x + a2.x + a3.x) * 0.25f;
        o.y = (a0.y + a1.y + a2.y + a3.y) * 0.25f;
        o.z = (a0.z + a1.z + a2.z + a3.z) * 0.25f;
        o.w = (a0.w + a1.w + a2.w + a3.w) * 0.25f;
        *(reinterpret_cast<float4*>(ob + (size_t)r * D_MODEL) + tid) = o;
    }
}

extern "C" void kernel_launch(void* const* d_in, const int* in_sizes, int n_in,
                              void* d_out, int out_size, void* d_ws, size_t ws_size,
                              hipStream_t stream) {
    const float* x  = (const float*)d_in[0];
    const float* Wq = (const float*)d_in[1];
    const float* bq = (const float*)d_in[2];
    const float* Wk = (const float*)d_in[3];
    const float* bk = (const float*)d_in[4];
    float* out = (float*)d_out;

    float* Qt = (float*)d_ws;                                  // [4][32][2048]
    float* Kt = Qt + (size_t)NBATCH * 32 * T_SEQ;              // [4][32][2048]  (2 MB total ws)

    proj_kernel<<<dim3(512), dim3(256), 0, stream>>>(x, Wq, bq, Wk, bk, Qt, Kt);
    topk_gather_kernel<<<dim3(512), dim3(256), 0, stream>>>(x, Qt, Kt, out);
}

// Round 2
// 179.704 us; speedup vs baseline: 1.6677x; 1.6677x over previous
//
#include <hip/hip_runtime.h>
#include <math.h>

#define D_MODEL 1024
#define T_SEQ   2048
#define NBATCH  4
#define NROWS   (NBATCH * T_SEQ)          // 8192
#define NOUT    64                        // 32 q + 32 k
#define DCHUNK  256
#define NCHUNK  4

#define SKLD 264   // klds row stride (floats): 256 + 8, 16B aligned, <=2-way banks
#define SQLD 20    // qlds row stride (floats)

// ---------- top-4 helpers: total order = (value desc, index asc) ----------
__device__ __forceinline__ bool key_gt(float av, int ai, float bv, int bi) {
    return (av > bv) || (av == bv && ai < bi);
}

__device__ __forceinline__ void cmpswap(float& v0, int& i0, float& v1, int& i1) {
    bool sw = key_gt(v1, i1, v0, i0);
    float nv0 = sw ? v1 : v0, nv1 = sw ? v0 : v1;
    int   ni0 = sw ? i1 : i0, ni1 = sw ? i0 : i1;
    v0 = nv0; v1 = nv1; i0 = ni0; i1 = ni1;
}

__device__ __forceinline__ void merge4(float (&a)[4], int (&ai)[4],
                                       float b0, int j0, float b1, int j1,
                                       float b2, int j2, float b3, int j3) {
    if (!key_gt(a[0], ai[0], b3, j3)) { a[0] = b3; ai[0] = j3; }
    if (!key_gt(a[1], ai[1], b2, j2)) { a[1] = b2; ai[1] = j2; }
    if (!key_gt(a[2], ai[2], b1, j1)) { a[2] = b1; ai[2] = j1; }
    if (!key_gt(a[3], ai[3], b0, j0)) { a[3] = b0; ai[3] = j0; }
    cmpswap(a[0], ai[0], a[2], ai[2]);
    cmpswap(a[1], ai[1], a[3], ai[3]);
    cmpswap(a[0], ai[0], a[1], ai[1]);
    cmpswap(a[2], ai[2], a[3], ai[3]);
}

__device__ __forceinline__ void insert4(float (&tv)[4], int (&tix)[4], float v, int idx) {
    if (v > tv[3]) {
        bool g0 = v > tv[0], g1 = v > tv[1], g2 = v > tv[2];
        float n0 = g0 ? v : tv[0];
        int   m0 = g0 ? idx : tix[0];
        float n1 = g1 ? (g0 ? tv[0] : v) : tv[1];
        int   m1 = g1 ? (g0 ? tix[0] : idx) : tix[1];
        float n2 = g2 ? (g1 ? tv[1] : v) : tv[2];
        int   m2 = g2 ? (g1 ? tix[1] : idx) : tix[2];
        float n3 = g2 ? tv[2] : v;
        int   m3 = g2 ? tix[2] : idx;
        tv[0] = n0; tv[1] = n1; tv[2] = n2; tv[3] = n3;
        tix[0] = m0; tix[1] = m1; tix[2] = m2; tix[3] = m3;
    }
}

// ---------- Phase 1a: convert W to f64, transposed Wdt[d][64] ----------
// Wdt[d][o] = Wq[o][d] (o<32), Wk[o-32][d] (o>=32)
__global__ __launch_bounds__(256) void wprep_kernel(
    const float* __restrict__ Wq, const float* __restrict__ Wk,
    double* __restrict__ Wdt)
{
    const int idx = blockIdx.x * 256 + threadIdx.x;   // 65536 total
    const int o = idx & 63;
    const int d = idx >> 6;
    float v = (o < 32) ? Wq[(size_t)o * D_MODEL + d]
                       : Wk[(size_t)(o - 32) * D_MODEL + d];
    Wdt[(size_t)d * 64 + o] = (double)v;
}

// ---------- Phase 1b: partial projection, fp64 accumulate ----------
// grid = NCHUNK * 128 row-blocks = 512 blocks x 256 thr (4 waves)
// thread: row = rb*64 + (tid&63); wave og = tid>>6 owns outputs [og*16, og*16+16)
// W addresses are wave-uniform -> scalar/broadcast loads, no per-use cvt.
__global__ __launch_bounds__(256) void proj_partial(
    const float* __restrict__ x, const double* __restrict__ Wdt,
    double* __restrict__ part /* [NCHUNK][NOUT][NROWS] */)
{
    const int rl = threadIdx.x & 63;
    const int og = __builtin_amdgcn_readfirstlane(threadIdx.x >> 6);  // wave-uniform
    const int rb = blockIdx.x & 127;
    const int c  = blockIdx.x >> 7;
    const int row = rb * 64 + rl;
    const int d0  = c * DCHUNK;

    const float4* xr = reinterpret_cast<const float4*>(x + (size_t)row * D_MODEL + d0);
    const double* wbase = Wdt + (size_t)d0 * 64 + og * 16;

    double acc[16];
    #pragma unroll
    for (int j = 0; j < 16; ++j) acc[j] = 0.0;

    #pragma unroll 2
    for (int i = 0; i < DCHUNK / 4; ++i) {
        float4 xv = xr[i];
        double xd[4] = {xv.x, xv.y, xv.z, xv.w};
        #pragma unroll
        for (int u = 0; u < 4; ++u) {
            const double* w = wbase + (size_t)(i * 4 + u) * 64;
            #pragma unroll
            for (int j = 0; j < 16; ++j)
                acc[j] = fma(xd[u], w[j], acc[j]);
        }
    }

    // part[c][og*16+j][row]; lanes (rows) contiguous -> coalesced 512B stores
    double* p = part + ((size_t)c * NOUT + og * 16) * NROWS + row;
    #pragma unroll
    for (int j = 0; j < 16; ++j)
        p[(size_t)j * NROWS] = acc[j];
}

// ---------- Phase 1c: combine chunks (fixed order -> deterministic), + bias ----------
// grid = NOUT*NROWS/256 = 2048 blocks
__global__ __launch_bounds__(256) void proj_combine(
    const double* __restrict__ part,
    const float* __restrict__ bq, const float* __restrict__ bk,
    float* __restrict__ Qt, float* __restrict__ Kt)
{
    const int idx = blockIdx.x * 256 + threadIdx.x;
    const int out = idx >> 13;        // 0..63
    const int row = idx & (NROWS - 1);
    double s = 0.0;
    #pragma unroll
    for (int c = 0; c < NCHUNK; ++c)
        s += part[((size_t)c * NOUT + out) * NROWS + row];
    const int b = row >> 11, t = row & 2047;
    if (out < 32) {
        Qt[((size_t)b * 32 + out) * T_SEQ + t] = (float)(s + (double)bq[out]);
    } else {
        Kt[((size_t)b * 32 + (out - 32)) * T_SEQ + t] = (float)(s + (double)bk[out - 32]);
    }
}

// ---------- Phase 2: sim = Q K^T, per-row top-4, fused gather+mean ----------
// grid 512 (= 4 batches * 128 t-tiles of 16), block 256 (4 waves)
__global__ __launch_bounds__(256) void topk_gather_kernel(
    const float* __restrict__ x, const float* __restrict__ Qt,
    const float* __restrict__ Kt, float* __restrict__ out)
{
    __shared__ float klds[32 * SKLD];     // K^T tile: [i][s], 33792 B
    __shared__ float qlds[32 * SQLD];     // Q^T tile: [i][t], 2560 B
    __shared__ float candV[4][16][4];
    __shared__ int   candI[4][16][4];
    __shared__ int   topIdx[16][4];

    const int tid  = threadIdx.x;
    const int lane = tid & 63;
    const int wav  = tid >> 6;
    const int b    = blockIdx.x >> 7;
    const int tblk = (blockIdx.x & 127) * 16;

    const float* QtB = Qt + (size_t)b * 32 * T_SEQ;
    const float* KtB = Kt + (size_t)b * 32 * T_SEQ;

    if (tid < 128) {
        const int i  = tid >> 2;
        const int t4 = (tid & 3) * 4;
        float4 v = *reinterpret_cast<const float4*>(QtB + (size_t)i * T_SEQ + tblk + t4);
        *reinterpret_cast<float4*>(&qlds[i * SQLD + t4]) = v;
    }

    const int tg = tid & 3;
    const int t0 = tg * 4;
    const int s0 = (tid >> 2) * 4;

    float tv[4][4]; int tix[4][4];
    #pragma unroll
    for (int r = 0; r < 4; ++r)
        #pragma unroll
        for (int j = 0; j < 4; ++j) { tv[r][j] = -INFINITY; tix[r][j] = 0x7fffffff; }

    for (int st = 0; st < 8; ++st) {
        __syncthreads();
        #pragma unroll
        for (int j = 0; j < 8; ++j) {
            const int f  = (tid + j * 256) * 4;
            const int ki = f >> 8;
            const int ks = f & 255;
            float4 v = *reinterpret_cast<const float4*>(KtB + (size_t)ki * T_SEQ + st * 256 + ks);
            *reinterpret_cast<float4*>(&klds[ki * SKLD + ks]) = v;
        }
        __syncthreads();

        float acc[4][4];
        #pragma unroll
        for (int r = 0; r < 4; ++r)
            #pragma unroll
            for (int c = 0; c < 4; ++c) acc[r][c] = 0.f;

        #pragma unroll 8
        for (int i = 0; i < 32; ++i) {
            float4 qv = *reinterpret_cast<const float4*>(&qlds[i * SQLD + t0]);
            float4 kv = *reinterpret_cast<const float4*>(&klds[i * SKLD + s0]);
            const float qa[4] = {qv.x, qv.y, qv.z, qv.w};
            const float ka[4] = {kv.x, kv.y, kv.z, kv.w};
            #pragma unroll
            for (int r = 0; r < 4; ++r)
                #pragma unroll
                for (int c = 0; c < 4; ++c)
                    acc[r][c] = fmaf(qa[r], ka[c], acc[r][c]);
        }

        const int sbase = st * 256 + s0;
        #pragma unroll
        for (int c = 0; c < 4; ++c)
            #pragma unroll
            for (int r = 0; r < 4; ++r)
                insert4(tv[r], tix[r], acc[r][c], sbase + c);
    }

    #pragma unroll
    for (int m = 4; m <= 32; m <<= 1) {
        #pragma unroll
        for (int r = 0; r < 4; ++r) {
            float b0 = __shfl_xor(tv[r][0], m, 64);
            float b1 = __shfl_xor(tv[r][1], m, 64);
            float b2 = __shfl_xor(tv[r][2], m, 64);
            float b3 = __shfl_xor(tv[r][3], m, 64);
            int   j0 = __shfl_xor(tix[r][0], m, 64);
            int   j1 = __shfl_xor(tix[r][1], m, 64);
            int   j2 = __shfl_xor(tix[r][2], m, 64);
            int   j3 = __shfl_xor(tix[r][3], m, 64);
            merge4(tv[r], tix[r], b0, j0, b1, j1, b2, j2, b3, j3);
        }
    }

    if (lane < 4) {
        #pragma unroll
        for (int r = 0; r < 4; ++r)
            #pragma unroll
            for (int j = 0; j < 4; ++j) {
                candV[wav][lane * 4 + r][j] = tv[r][j];
                candI[wav][lane * 4 + r][j] = tix[r][j];
            }
    }
    __syncthreads();

    if (tid < 16) {
        float mv[4]; int mi[4];
        #pragma unroll
        for (int j = 0; j < 4; ++j) { mv[j] = candV[0][tid][j]; mi[j] = candI[0][tid][j]; }
        #pragma unroll
        for (int w = 1; w < 4; ++w)
            merge4(mv, mi,
                   candV[w][tid][0], candI[w][tid][0],
                   candV[w][tid][1], candI[w][tid][1],
                   candV[w][tid][2], candI[w][tid][2],
                   candV[w][tid][3], candI[w][tid][3]);
        #pragma unroll
        for (int j = 0; j < 4; ++j) topIdx[tid][j] = mi[j];
    }
    __syncthreads();

    const float* xb = x + (size_t)b * T_SEQ * D_MODEL;
    float* ob = out + ((size_t)b * T_SEQ + tblk) * D_MODEL;
    for (int r = 0; r < 16; ++r) {
        const int i0 = topIdx[r][0], i1 = topIdx[r][1], i2 = topIdx[r][2], i3 = topIdx[r][3];
        float4 a0 = *(reinterpret_cast<const float4*>(xb + (size_t)i0 * D_MODEL) + tid);
        float4 a1 = *(reinterpret_cast<const float4*>(xb + (size_t)i1 * D_MODEL) + tid);
        float4 a2 = *(reinterpret_cast<const float4*>(xb + (size_t)i2 * D_MODEL) + tid);
        float4 a3 = *(reinterpret_cast<const float4*>(xb + (size_t)i3 * D_MODEL) + tid);
        float4 o;
        o.x = (a0.x + a1.x + a2.x + a3.x) * 0.25f;
        o.y = (a0.y + a1.y + a2.y + a3.y) * 0.25f;
        o.z = (a0.z + a1.z + a2.z + a3.z) * 0.25f;
        o.w = (a0.w + a1.w + a2.w + a3.w) * 0.25f;
        *(reinterpret_cast<float4*>(ob + (size_t)r * D_MODEL) + tid) = o;
    }
}

extern "C" void kernel_launch(void* const* d_in, const int* in_sizes, int n_in,
                              void* d_out, int out_size, void* d_ws, size_t ws_size,
                              hipStream_t stream) {
    const float* x  = (const float*)d_in[0];
    const float* Wq = (const float*)d_in[1];
    const float* bq = (const float*)d_in[2];
    const float* Wk = (const float*)d_in[3];
    const float* bk = (const float*)d_in[4];
    float* out = (float*)d_out;

    // ws layout: [Wdt 512KB f64][Qt 1MB f32][Kt 1MB f32][part 16MB f64]
    char* wsb = (char*)d_ws;
    double* Wdt  = (double*)wsb;                                    // 1024*64*8   = 512 KB
    float*  Qt   = (float*)(wsb + (size_t)D_MODEL * NOUT * 8);      // 4*32*2048*4 = 1 MB
    float*  Kt   = Qt + (size_t)NBATCH * 32 * T_SEQ;
    double* part = (double*)(wsb + (size_t)D_MODEL * NOUT * 8
                                 + 2 * (size_t)NBATCH * 32 * T_SEQ * 4);  // 16 MB

    wprep_kernel<<<dim3(256), dim3(256), 0, stream>>>(Wq, Wk, Wdt);
    proj_partial<<<dim3(NCHUNK * 128), dim3(256), 0, stream>>>(x, Wdt, part);
    proj_combine<<<dim3(NOUT * NROWS / 256), dim3(256), 0, stream>>>(part, bq, bk, Qt, Kt);
    topk_gather_kernel<<<dim3(512), dim3(256), 0, stream>>>(x, Qt, Kt, out);
}

// Round 3
// 173.773 us; speedup vs baseline: 1.7246x; 1.0341x over previous
//
#include <hip/hip_runtime.h>
#include <math.h>

#define D_MODEL 1024
#define T_SEQ   2048
#define NBATCH  4
#define NROWS   (NBATCH * T_SEQ)          // 8192
#define NOUT    64                        // 32 q + 32 k
#define DCHUNK  256
#define NCHUNK  4

#define SKLD 264   // klds row stride (floats): 256 + 8, 16B aligned, <=2-way banks
#define SQLD 20    // qlds row stride (floats)

// ---------- top-4 helpers: total order = (value desc, index asc) ----------
__device__ __forceinline__ bool key_gt(float av, int ai, float bv, int bi) {
    return (av > bv) || (av == bv && ai < bi);
}

__device__ __forceinline__ void cmpswap(float& v0, int& i0, float& v1, int& i1) {
    bool sw = key_gt(v1, i1, v0, i0);
    float nv0 = sw ? v1 : v0, nv1 = sw ? v0 : v1;
    int   ni0 = sw ? i1 : i0, ni1 = sw ? i0 : i1;
    v0 = nv0; v1 = nv1; i0 = ni0; i1 = ni1;
}

// merge sorted-desc a[4] with sorted-desc b[4] -> top4 of union into a (bitonic)
__device__ __forceinline__ void merge4(float (&a)[4], int (&ai)[4],
                                       float b0, int j0, float b1, int j1,
                                       float b2, int j2, float b3, int j3) {
    if (!key_gt(a[0], ai[0], b3, j3)) { a[0] = b3; ai[0] = j3; }
    if (!key_gt(a[1], ai[1], b2, j2)) { a[1] = b2; ai[1] = j2; }
    if (!key_gt(a[2], ai[2], b1, j1)) { a[2] = b1; ai[2] = j1; }
    if (!key_gt(a[3], ai[3], b0, j0)) { a[3] = b0; ai[3] = j0; }
    cmpswap(a[0], ai[0], a[2], ai[2]);
    cmpswap(a[1], ai[1], a[3], ai[3]);
    cmpswap(a[0], ai[0], a[1], ai[1]);
    cmpswap(a[2], ai[2], a[3], ai[3]);
}

// insert candidate (v, idx) into sorted-desc top4; strict > keeps earlier index on ties
__device__ __forceinline__ void insert4(float (&tv)[4], int (&tix)[4], float v, int idx) {
    if (v > tv[3]) {
        bool g0 = v > tv[0], g1 = v > tv[1], g2 = v > tv[2];
        float n0 = g0 ? v : tv[0];
        int   m0 = g0 ? idx : tix[0];
        float n1 = g1 ? (g0 ? tv[0] : v) : tv[1];
        int   m1 = g1 ? (g0 ? tix[0] : idx) : tix[1];
        float n2 = g2 ? (g1 ? tv[1] : v) : tv[2];
        int   m2 = g2 ? (g1 ? tix[1] : idx) : tix[2];
        float n3 = g2 ? tv[2] : v;
        int   m3 = g2 ? tix[2] : idx;
        tv[0] = n0; tv[1] = n1; tv[2] = n2; tv[3] = n3;
        tix[0] = m0; tix[1] = m1; tix[2] = m2; tix[3] = m3;
    }
}

// ---------- Phase 1a: convert W to f64, transposed Wdt[d][64] ----------
__global__ __launch_bounds__(256) void wprep_kernel(
    const float* __restrict__ Wq, const float* __restrict__ Wk,
    double* __restrict__ Wdt)
{
    const int idx = blockIdx.x * 256 + threadIdx.x;   // 65536 total
    const int o = idx & 63;
    const int d = idx >> 6;
    float v = (o < 32) ? Wq[(size_t)o * D_MODEL + d]
                       : Wk[(size_t)(o - 32) * D_MODEL + d];
    Wdt[(size_t)d * 64 + o] = (double)v;
}

// ---------- Phase 1b: partial projection, fp64 accumulate ----------
// grid = NCHUNK * 128 = 512 blocks x 512 thr (8 waves) -> 16 waves/CU
// wave og owns outputs [og*8, og*8+8); per-thread 8 independent f64 chains.
// d-sequential chain order identical to prior rounds -> bitwise-identical part.
__global__ __launch_bounds__(512) void proj_partial(
    const float* __restrict__ x, const double* __restrict__ Wdt,
    double* __restrict__ part /* [NCHUNK][NOUT][NROWS] */)
{
    const int rl = threadIdx.x & 63;
    const int og = __builtin_amdgcn_readfirstlane(threadIdx.x >> 6);  // wave-uniform 0..7
    const int rb = blockIdx.x & 127;
    const int c  = blockIdx.x >> 7;
    const int row = rb * 64 + rl;
    const int d0  = c * DCHUNK;

    const float4* xr = reinterpret_cast<const float4*>(x + (size_t)row * D_MODEL + d0);
    const double* wbase = Wdt + (size_t)d0 * 64 + og * 8;

    double acc[8];
    #pragma unroll
    for (int j = 0; j < 8; ++j) acc[j] = 0.0;

    #pragma unroll 4
    for (int i = 0; i < DCHUNK / 4; ++i) {
        float4 xv = xr[i];
        double xd[4] = {xv.x, xv.y, xv.z, xv.w};
        #pragma unroll
        for (int u = 0; u < 4; ++u) {
            const double* w = wbase + (size_t)(i * 4 + u) * 64;
            #pragma unroll
            for (int j = 0; j < 8; ++j)
                acc[j] = fma(xd[u], w[j], acc[j]);
        }
    }

    double* p = part + ((size_t)c * NOUT + og * 8) * NROWS + row;
    #pragma unroll
    for (int j = 0; j < 8; ++j)
        p[(size_t)j * NROWS] = acc[j];
}

// ---------- Phase 1c: combine chunks (fixed order), + bias ----------
__global__ __launch_bounds__(256) void proj_combine(
    const double* __restrict__ part,
    const float* __restrict__ bq, const float* __restrict__ bk,
    float* __restrict__ Qt, float* __restrict__ Kt)
{
    const int idx = blockIdx.x * 256 + threadIdx.x;
    const int out = idx >> 13;        // 0..63
    const int row = idx & (NROWS - 1);
    double s = 0.0;
    #pragma unroll
    for (int c = 0; c < NCHUNK; ++c)
        s += part[((size_t)c * NOUT + out) * NROWS + row];
    const int b = row >> 11, t = row & 2047;
    if (out < 32) {
        Qt[((size_t)b * 32 + out) * T_SEQ + t] = (float)(s + (double)bq[out]);
    } else {
        Kt[((size_t)b * 32 + (out - 32)) * T_SEQ + t] = (float)(s + (double)bk[out - 32]);
    }
}

// ---------- Phase 2a: sim over an s-half, per-row top-4 -> ws ----------
// grid 1024 = b(4) x ttile(128) x half(2); block 128 thr (2 waves)
// micro-tile 4t x 8s: per i, 1 q-b128 + 2 k-b128 feed 32 FMA
// LDS 37.4 KB -> 4 blocks/CU = 8 waves/CU at grid 1024
__global__ __launch_bounds__(128) void sim_topk(
    const float* __restrict__ Qt, const float* __restrict__ Kt,
    float* __restrict__ candVal /* [2][NROWS][4] */,
    int*   __restrict__ candIdx /* [2][NROWS][4] */)
{
    __shared__ float klds[32 * SKLD];     // 33792 B
    __shared__ float qlds[32 * SQLD];     // 2560 B
    __shared__ float cV[2][16][4];
    __shared__ int   cI[2][16][4];

    const int tid  = threadIdx.x;
    const int lane = tid & 63;
    const int wav  = tid >> 6;            // 0..1
    const int half = blockIdx.x & 1;
    const int tt   = (blockIdx.x >> 1) & 127;
    const int b    = blockIdx.x >> 8;
    const int tblk = tt * 16;
    const int sh0  = half * 1024;

    const float* QtB = Qt + (size_t)b * 32 * T_SEQ;
    const float* KtB = Kt + (size_t)b * 32 * T_SEQ;

    // stage Q^T tile: 32 i x 16 t (exactly 128 float4s)
    {
        const int i  = tid >> 2;
        const int t4 = (tid & 3) * 4;
        float4 v = *reinterpret_cast<const float4*>(QtB + (size_t)i * T_SEQ + tblk + t4);
        *reinterpret_cast<float4*>(&qlds[i * SQLD + t4]) = v;
    }

    const int tg = tid & 3;
    const int t0 = tg * 4;
    const int s0 = (tid >> 2) * 8;        // 32 s-groups x 8

    float tv[4][4]; int tix[4][4];
    #pragma unroll
    for (int r = 0; r < 4; ++r)
        #pragma unroll
        for (int j = 0; j < 4; ++j) { tv[r][j] = -INFINITY; tix[r][j] = 0x7fffffff; }

    for (int st = 0; st < 4; ++st) {
        __syncthreads();
        // stage K^T tile: 32 i x 256 s (2048 float4s, 16/thread), coalesced
        #pragma unroll
        for (int j = 0; j < 16; ++j) {
            const int f  = (tid + j * 128) * 4;
            const int ki = f >> 8;
            const int ks = f & 255;
            float4 v = *reinterpret_cast<const float4*>(
                KtB + (size_t)ki * T_SEQ + sh0 + st * 256 + ks);
            *reinterpret_cast<float4*>(&klds[ki * SKLD + ks]) = v;
        }
        __syncthreads();

        float acc[4][8];
        #pragma unroll
        for (int r = 0; r < 4; ++r)
            #pragma unroll
            for (int c = 0; c < 8; ++c) acc[r][c] = 0.f;

        #pragma unroll 4
        for (int i = 0; i < 32; ++i) {
            float4 qv  = *reinterpret_cast<const float4*>(&qlds[i * SQLD + t0]);
            float4 kv0 = *reinterpret_cast<const float4*>(&klds[i * SKLD + s0]);
            float4 kv1 = *reinterpret_cast<const float4*>(&klds[i * SKLD + s0 + 4]);
            const float qa[4] = {qv.x, qv.y, qv.z, qv.w};
            const float ka[8] = {kv0.x, kv0.y, kv0.z, kv0.w, kv1.x, kv1.y, kv1.z, kv1.w};
            #pragma unroll
            for (int r = 0; r < 4; ++r)
                #pragma unroll
                for (int c = 0; c < 8; ++c)
                    acc[r][c] = fmaf(qa[r], ka[c], acc[r][c]);
        }

        const int sbase = sh0 + st * 256 + s0;
        #pragma unroll
        for (int c = 0; c < 8; ++c)
            #pragma unroll
            for (int r = 0; r < 4; ++r)
                insert4(tv[r], tix[r], acc[r][c], sbase + c);
    }

    // wave butterfly: masks 4..32 preserve tg = lane&3 (row ownership)
    #pragma unroll
    for (int m = 4; m <= 32; m <<= 1) {
        #pragma unroll
        for (int r = 0; r < 4; ++r) {
            float b0 = __shfl_xor(tv[r][0], m, 64);
            float b1 = __shfl_xor(tv[r][1], m, 64);
            float b2 = __shfl_xor(tv[r][2], m, 64);
            float b3 = __shfl_xor(tv[r][3], m, 64);
            int   j0 = __shfl_xor(tix[r][0], m, 64);
            int   j1 = __shfl_xor(tix[r][1], m, 64);
            int   j2 = __shfl_xor(tix[r][2], m, 64);
            int   j3 = __shfl_xor(tix[r][3], m, 64);
            merge4(tv[r], tix[r], b0, j0, b1, j1, b2, j2, b3, j3);
        }
    }

    if (lane < 4) {
        #pragma unroll
        for (int r = 0; r < 4; ++r)
            #pragma unroll
            for (int j = 0; j < 4; ++j) {
                cV[wav][lane * 4 + r][j] = tv[r][j];
                cI[wav][lane * 4 + r][j] = tix[r][j];
            }
    }
    __syncthreads();

    // cross-wave merge (2 waves), write per-half candidate lists
    if (tid < 16) {
        float mv[4]; int mi[4];
        #pragma unroll
        for (int j = 0; j < 4; ++j) { mv[j] = cV[0][tid][j]; mi[j] = cI[0][tid][j]; }
        merge4(mv, mi,
               cV[1][tid][0], cI[1][tid][0],
               cV[1][tid][1], cI[1][tid][1],
               cV[1][tid][2], cI[1][tid][2],
               cV[1][tid][3], cI[1][tid][3]);
        const size_t row = (size_t)b * T_SEQ + tblk + tid;
        float4 vv = {mv[0], mv[1], mv[2], mv[3]};
        int4   ii = {mi[0], mi[1], mi[2], mi[3]};
        *reinterpret_cast<float4*>(candVal + ((size_t)half * NROWS + row) * 4) = vv;
        *reinterpret_cast<int4*>(candIdx + ((size_t)half * NROWS + row) * 4) = ii;
    }
}

// ---------- Phase 2b: merge halves + fused gather/mean ----------
// grid 1024 (8 rows/block), block 256 thr
__global__ __launch_bounds__(256) void merge_gather(
    const float* __restrict__ x,
    const float* __restrict__ candVal, const int* __restrict__ candIdx,
    float* __restrict__ out)
{
    __shared__ int topIdx[8][4];

    const int tid  = threadIdx.x;
    const int row0 = blockIdx.x * 8;      // 8 rows, same batch (8 | 2048)
    const int b    = row0 >> 11;

    if (tid < 8) {
        const size_t row = row0 + tid;
        float4 v0 = *reinterpret_cast<const float4*>(candVal + row * 4);
        int4   i0 = *reinterpret_cast<const int4*>(candIdx + row * 4);
        float4 v1 = *reinterpret_cast<const float4*>(candVal + ((size_t)NROWS + row) * 4);
        int4   i1 = *reinterpret_cast<const int4*>(candIdx + ((size_t)NROWS + row) * 4);
        float mv[4] = {v0.x, v0.y, v0.z, v0.w};
        int   mi[4] = {i0.x, i0.y, i0.z, i0.w};
        merge4(mv, mi, v1.x, i1.x, v1.y, i1.y, v1.z, i1.z, v1.w, i1.w);
        #pragma unroll
        for (int j = 0; j < 4; ++j) topIdx[tid][j] = mi[j];
    }
    __syncthreads();

    const float* xb = x + (size_t)b * T_SEQ * D_MODEL;
    float* ob = out + (size_t)row0 * D_MODEL;
    #pragma unroll
    for (int r = 0; r < 8; ++r) {
        const int i0 = topIdx[r][0], i1 = topIdx[r][1], i2 = topIdx[r][2], i3 = topIdx[r][3];
        float4 a0 = *(reinterpret_cast<const float4*>(xb + (size_t)i0 * D_MODEL) + tid);
        float4 a1 = *(reinterpret_cast<const float4*>(xb + (size_t)i1 * D_MODEL) + tid);
        float4 a2 = *(reinterpret_cast<const float4*>(xb + (size_t)i2 * D_MODEL) + tid);
        float4 a3 = *(reinterpret_cast<const float4*>(xb + (size_t)i3 * D_MODEL) + tid);
        float4 o;
        o.x = (a0.x + a1.x + a2.x + a3.x) * 0.25f;
        o.y = (a0.y + a1.y + a2.y + a3.y) * 0.25f;
        o.z = (a0.z + a1.z + a2.z + a3.z) * 0.25f;
        o.w = (a0.w + a1.w + a2.w + a3.w) * 0.25f;
        *(reinterpret_cast<float4*>(ob + (size_t)r * D_MODEL) + tid) = o;
    }
}

extern "C" void kernel_launch(void* const* d_in, const int* in_sizes, int n_in,
                              void* d_out, int out_size, void* d_ws, size_t ws_size,
                              hipStream_t stream) {
    const float* x  = (const float*)d_in[0];
    const float* Wq = (const float*)d_in[1];
    const float* bq = (const float*)d_in[2];
    const float* Wk = (const float*)d_in[3];
    const float* bk = (const float*)d_in[4];
    float* out = (float*)d_out;

    // ws layout: [Wdt 512KB][Qt 1MB][Kt 1MB][part 16MB][candVal 256KB][candIdx 256KB]
    char* wsb = (char*)d_ws;
    double* Wdt  = (double*)wsb;                                         // 512 KB
    float*  Qt   = (float*)(wsb + (size_t)D_MODEL * NOUT * 8);           // 1 MB
    float*  Kt   = Qt + (size_t)NBATCH * 32 * T_SEQ;                     // 1 MB
    double* part = (double*)(wsb + (size_t)D_MODEL * NOUT * 8
                                 + 2 * (size_t)NBATCH * 32 * T_SEQ * 4); // 16 MB
    float*  candVal = (float*)((char*)part + (size_t)NCHUNK * NOUT * NROWS * 8);
    int*    candIdx = (int*)((char*)candVal + (size_t)2 * NROWS * 4 * 4);

    wprep_kernel<<<dim3(256), dim3(256), 0, stream>>>(Wq, Wk, Wdt);
    proj_partial<<<dim3(NCHUNK * 128), dim3(512), 0, stream>>>(x, Wdt, part);
    proj_combine<<<dim3(NOUT * NROWS / 256), dim3(256), 0, stream>>>(part, bq, bk, Qt, Kt);
    sim_topk<<<dim3(1024), dim3(128), 0, stream>>>(Qt, Kt, candVal, candIdx);
    merge_gather<<<dim3(1024), dim3(256), 0, stream>>>(x, candVal, candIdx, out);
}

// Round 5
// 170.982 us; speedup vs baseline: 1.7527x; 1.0163x over previous
//
#include <hip/hip_runtime.h>
#include <math.h>

#define D_MODEL 1024
#define T_SEQ   2048
#define NBATCH  4
#define NROWS   (NBATCH * T_SEQ)          // 8192
#define NOUT    64                        // 32 q + 32 k

#define SKLD 264   // klds row stride (floats): 256 + 8, 16B aligned, <=2-way banks
#define SQLD 20    // qlds row stride (floats)
#define XLD  260   // xlds row stride (floats): 256 + 4, 16B aligned

typedef double v4df __attribute__((ext_vector_type(4)));

// ---------- top-4 helpers: total order = (value desc, index asc) ----------
__device__ __forceinline__ bool key_gt(float av, int ai, float bv, int bi) {
    return (av > bv) || (av == bv && ai < bi);
}

__device__ __forceinline__ void cmpswap(float& v0, int& i0, float& v1, int& i1) {
    bool sw = key_gt(v1, i1, v0, i0);
    float nv0 = sw ? v1 : v0, nv1 = sw ? v0 : v1;
    int   ni0 = sw ? i1 : i0, ni1 = sw ? i0 : i1;
    v0 = nv0; v1 = nv1; i0 = ni0; i1 = ni1;
}

// merge sorted-desc a[4] with sorted-desc b[4] -> top4 of union into a (bitonic)
__device__ __forceinline__ void merge4(float (&a)[4], int (&ai)[4],
                                       float b0, int j0, float b1, int j1,
                                       float b2, int j2, float b3, int j3) {
    if (!key_gt(a[0], ai[0], b3, j3)) { a[0] = b3; ai[0] = j3; }
    if (!key_gt(a[1], ai[1], b2, j2)) { a[1] = b2; ai[1] = j2; }
    if (!key_gt(a[2], ai[2], b1, j1)) { a[2] = b1; ai[2] = j1; }
    if (!key_gt(a[3], ai[3], b0, j0)) { a[3] = b0; ai[3] = j0; }
    cmpswap(a[0], ai[0], a[2], ai[2]);
    cmpswap(a[1], ai[1], a[3], ai[3]);
    cmpswap(a[0], ai[0], a[1], ai[1]);
    cmpswap(a[2], ai[2], a[3], ai[3]);
}

// insert candidate (v, idx) into sorted-desc top4; strict > keeps earlier index on ties
__device__ __forceinline__ void insert4(float (&tv)[4], int (&tix)[4], float v, int idx) {
    if (v > tv[3]) {
        bool g0 = v > tv[0], g1 = v > tv[1], g2 = v > tv[2];
        float n0 = g0 ? v : tv[0];
        int   m0 = g0 ? idx : tix[0];
        float n1 = g1 ? (g0 ? tv[0] : v) : tv[1];
        int   m1 = g1 ? (g0 ? tix[0] : idx) : tix[1];
        float n2 = g2 ? (g1 ? tv[1] : v) : tv[2];
        int   m2 = g2 ? (g1 ? tix[1] : idx) : tix[2];
        float n3 = g2 ? tv[2] : v;
        int   m3 = g2 ? tix[2] : idx;
        tv[0] = n0; tv[1] = n1; tv[2] = n2; tv[3] = n3;
        tix[0] = m0; tix[1] = m1; tix[2] = m2; tix[3] = m3;
    }
}

// ---------- Phase 0: probe the f64 MFMA fragment layout in-device ----------
// 1 wave. Builds asymmetric integer A(16x4), B(4x16) (exact in f64), computes
// scalar reference D, then tests 16 (fA,fB,fD) hypotheses against the real
// instruction. Writes per-lane index tables + flag to ws.
// tab layout (ints): [0]=flag, [1..64]=am, [65..128]=ak, [129..192]=bk,
//                    [193..256]=bn, [257..512]=dm[lane][4], [513..768]=dn[lane][4]
__global__ __launch_bounds__(64) void mfma_probe(int* __restrict__ tab)
{
    __shared__ double Aref[16][4];
    __shared__ double Bref[4][16];
    __shared__ double Dref[16][16];

    const int lane = threadIdx.x;
    {
        const int m = lane & 15, k = lane >> 4;
        Aref[m][k] = (double)(1 + m * 4 + k);     // distinct 1..64, asymmetric
        Bref[k][m] = (double)(1 + k * 16 + m);    // distinct 1..64, asymmetric
    }
    __syncthreads();
    for (int e = lane; e < 256; e += 64) {
        const int m = e >> 4, n = e & 15;
        double s = 0.0;
        for (int k = 0; k < 4; ++k) s += Aref[m][k] * Bref[k][n];
        Dref[m][n] = s;   // exact integer-valued f64 -> order-independent
    }
    __syncthreads();

    int found = -1;
    for (int h = 0; h < 16; ++h) {
        if (found >= 0) break;                     // uniform
        const int fa = h & 1, fb = (h >> 1) & 1, fd = h >> 2;
        const int am = fa ? (lane >> 2) : (lane & 15);
        const int ak = fa ? (lane & 3)  : (lane >> 4);
        const int bn = fb ? (lane >> 2) : (lane & 15);
        const int bk = fb ? (lane & 3)  : (lane >> 4);
        v4df c = {0.0, 0.0, 0.0, 0.0};
        c = __builtin_amdgcn_mfma_f64_16x16x4f64(Aref[am][ak], Bref[bk][bn], c, 0, 0, 0);
        bool ok = true;
        #pragma unroll
        for (int i = 0; i < 4; ++i) {
            int dm, dn;
            if (fd == 0)      { dm = 4 * (lane >> 4) + i; dn = lane & 15; }
            else if (fd == 1) { dn = 4 * (lane >> 4) + i; dm = lane & 15; }
            else if (fd == 2) { dm = (lane >> 4) + 4 * i; dn = lane & 15; }
            else              { dn = (lane >> 4) + 4 * i; dm = lane & 15; }
            if (c[i] != Dref[dm][dn]) ok = false;  // exact: all values integer
        }
        if (__all(ok)) found = h;
    }

    const int fa = (found >= 0) ? (found & 1) : 0;
    const int fb = (found >= 0) ? ((found >> 1) & 1) : 0;
    const int fd = (found >= 0) ? (found >> 2) : 0;
    tab[1   + lane] = fa ? (lane >> 2) : (lane & 15);
    tab[65  + lane] = fa ? (lane & 3)  : (lane >> 4);
    tab[129 + lane] = fb ? (lane & 3)  : (lane >> 4);
    tab[193 + lane] = fb ? (lane >> 2) : (lane & 15);
    #pragma unroll
    for (int i = 0; i < 4; ++i) {
        int dm, dn;
        if (fd == 0)      { dm = 4 * (lane >> 4) + i; dn = lane & 15; }
        else if (fd == 1) { dn = 4 * (lane >> 4) + i; dm = lane & 15; }
        else if (fd == 2) { dm = (lane >> 4) + 4 * i; dn = lane & 15; }
        else              { dn = (lane >> 4) + 4 * i; dm = lane & 15; }
        tab[257 + lane * 4 + i] = dm;
        tab[513 + lane * 4 + i] = dn;
    }
    if (lane == 0) tab[0] = found;
}

// ---------- Phase 1a: convert W to f64, transposed Wdt[d][64] ----------
__global__ __launch_bounds__(256) void wprep_kernel(
    const float* __restrict__ Wq, const float* __restrict__ Wk,
    double* __restrict__ Wdt)
{
    const int idx = blockIdx.x * 256 + threadIdx.x;   // 65536 total
    const int o = idx & 63;
    const int d = idx >> 6;
    float v = (o < 32) ? Wq[(size_t)o * D_MODEL + d]
                       : Wk[(size_t)(o - 32) * D_MODEL + d];
    Wdt[(size_t)d * 64 + o] = (double)v;
}

// ---------- Phase 1b: projection via f64 MFMA, table-driven layout ----------
// grid 512 (= 8192 rows / 16), block 256 (4 waves). Wave og owns out-tile og*16.
// Fragment indices come from the probe's tables -> correct under ANY of the
// 16 candidate layouts. flag<0 => scalar-f64 fallback (D0 output mapping,
// matching the placeholder tables).
__global__ __launch_bounds__(256) void proj_mfma(
    const float* __restrict__ x, const double* __restrict__ Wdt,
    const float* __restrict__ bq, const float* __restrict__ bk_,
    const int* __restrict__ tab,
    float* __restrict__ Qt, float* __restrict__ Kt)
{
    __shared__ float xlds[16 * XLD];      // 16 rows x 256 d staged, 16640 B

    const int tid  = threadIdx.x;
    const int lane = tid & 63;
    const int og   = __builtin_amdgcn_readfirstlane(tid >> 6);   // 0..3
    const int row0 = blockIdx.x * 16;

    const int flag = tab[0];
    const int am  = tab[1   + lane];
    const int ak  = tab[65  + lane];
    const int bkk = tab[129 + lane];
    const int bn  = tab[193 + lane];

    const double* wcol = Wdt + og * 16;   // + d*64 + bn

    v4df acc = {0.0, 0.0, 0.0, 0.0};

    for (int st = 0; st < 4; ++st) {
        __syncthreads();   // previous stage fully consumed
        // stage x tile: 16 rows x 256 d (1024 float4s, 4/thread), coalesced
        #pragma unroll
        for (int j = 0; j < 4; ++j) {
            const int f  = j * 256 + tid;
            const int r  = f >> 6;          // 0..15
            const int c4 = f & 63;          // float4 within row
            float4 v = *reinterpret_cast<const float4*>(
                x + (size_t)(row0 + r) * D_MODEL + st * 256 + c4 * 4);
            *reinterpret_cast<float4*>(&xlds[r * XLD + c4 * 4]) = v;
        }
        __syncthreads();

        if (flag >= 0) {
            // 64 chained MFMAs over this stage's 256 d (k ascending)
            #pragma unroll 8
            for (int kk = 0; kk < 64; ++kk) {
                double a = (double)xlds[am * XLD + kk * 4 + ak];
                double b = wcol[(size_t)(st * 256 + kk * 4 + bkk) * 64 + bn];
                acc = __builtin_amdgcn_mfma_f64_16x16x4f64(a, b, acc, 0, 0, 0);
            }
        } else {
            // scalar f64 fallback: out n = lane&15, rows 4*(lane>>4)+i
            const int n  = lane & 15;
            const int r4 = (lane >> 4) * 4;
            for (int dd = 0; dd < 256; ++dd) {
                double wv = wcol[(size_t)(st * 256 + dd) * 64 + n];
                #pragma unroll
                for (int i = 0; i < 4; ++i)
                    acc[i] = fma((double)xlds[(r4 + i) * XLD + dd], wv, acc[i]);
            }
        }
    }

    // epilogue: + bias (f64, before f32 round), store per probed D-mapping
    #pragma unroll
    for (int i = 0; i < 4; ++i) {
        const int dmv = tab[257 + lane * 4 + i];
        const int dnv = tab[513 + lane * 4 + i];
        const int out = og * 16 + dnv;
        const int row = row0 + dmv;
        const int bb  = row >> 11, t = row & 2047;
        const double bias = (out < 32) ? (double)bq[out] : (double)bk_[out - 32];
        const float v = (float)(acc[i] + bias);
        if (out < 32) Qt[((size_t)bb * 32 + out) * T_SEQ + t] = v;
        else          Kt[((size_t)bb * 32 + (out - 32)) * T_SEQ + t] = v;
    }
}

// ---------- Phase 2a: sim over an s-half, per-row top-4 -> ws (UNCHANGED) ----------
__global__ __launch_bounds__(128) void sim_topk(
    const float* __restrict__ Qt, const float* __restrict__ Kt,
    float* __restrict__ candVal /* [2][NROWS][4] */,
    int*   __restrict__ candIdx /* [2][NROWS][4] */)
{
    __shared__ float klds[32 * SKLD];     // 33792 B
    __shared__ float qlds[32 * SQLD];     // 2560 B
    __shared__ float cV[2][16][4];
    __shared__ int   cI[2][16][4];

    const int tid  = threadIdx.x;
    const int lane = tid & 63;
    const int wav  = tid >> 6;            // 0..1
    const int half = blockIdx.x & 1;
    const int tt   = (blockIdx.x >> 1) & 127;
    const int b    = blockIdx.x >> 8;
    const int tblk = tt * 16;
    const int sh0  = half * 1024;

    const float* QtB = Qt + (size_t)b * 32 * T_SEQ;
    const float* KtB = Kt + (size_t)b * 32 * T_SEQ;

    {
        const int i  = tid >> 2;
        const int t4 = (tid & 3) * 4;
        float4 v = *reinterpret_cast<const float4*>(QtB + (size_t)i * T_SEQ + tblk + t4);
        *reinterpret_cast<float4*>(&qlds[i * SQLD + t4]) = v;
    }

    const int tg = tid & 3;
    const int t0 = tg * 4;
    const int s0 = (tid >> 2) * 8;

    float tv[4][4]; int tix[4][4];
    #pragma unroll
    for (int r = 0; r < 4; ++r)
        #pragma unroll
        for (int j = 0; j < 4; ++j) { tv[r][j] = -INFINITY; tix[r][j] = 0x7fffffff; }

    for (int st = 0; st < 4; ++st) {
        __syncthreads();
        #pragma unroll
        for (int j = 0; j < 16; ++j) {
            const int f  = (tid + j * 128) * 4;
            const int ki = f >> 8;
            const int ks = f & 255;
            float4 v = *reinterpret_cast<const float4*>(
                KtB + (size_t)ki * T_SEQ + sh0 + st * 256 + ks);
            *reinterpret_cast<float4*>(&klds[ki * SKLD + ks]) = v;
        }
        __syncthreads();

        float acc[4][8];
        #pragma unroll
        for (int r = 0; r < 4; ++r)
            #pragma unroll
            for (int c = 0; c < 8; ++c) acc[r][c] = 0.f;

        #pragma unroll 4
        for (int i = 0; i < 32; ++i) {
            float4 qv  = *reinterpret_cast<const float4*>(&qlds[i * SQLD + t0]);
            float4 kv0 = *reinterpret_cast<const float4*>(&klds[i * SKLD + s0]);
            float4 kv1 = *reinterpret_cast<const float4*>(&klds[i * SKLD + s0 + 4]);
            const float qa[4] = {qv.x, qv.y, qv.z, qv.w};
            const float ka[8] = {kv0.x, kv0.y, kv0.z, kv0.w, kv1.x, kv1.y, kv1.z, kv1.w};
            #pragma unroll
            for (int r = 0; r < 4; ++r)
                #pragma unroll
                for (int c = 0; c < 8; ++c)
                    acc[r][c] = fmaf(qa[r], ka[c], acc[r][c]);
        }

        const int sbase = sh0 + st * 256 + s0;
        #pragma unroll
        for (int c = 0; c < 8; ++c)
            #pragma unroll
            for (int r = 0; r < 4; ++r)
                insert4(tv[r], tix[r], acc[r][c], sbase + c);
    }

    #pragma unroll
    for (int m = 4; m <= 32; m <<= 1) {
        #pragma unroll
        for (int r = 0; r < 4; ++r) {
            float b0 = __shfl_xor(tv[r][0], m, 64);
            float b1 = __shfl_xor(tv[r][1], m, 64);
            float b2 = __shfl_xor(tv[r][2], m, 64);
            float b3 = __shfl_xor(tv[r][3], m, 64);
            int   j0 = __shfl_xor(tix[r][0], m, 64);
            int   j1 = __shfl_xor(tix[r][1], m, 64);
            int   j2 = __shfl_xor(tix[r][2], m, 64);
            int   j3 = __shfl_xor(tix[r][3], m, 64);
            merge4(tv[r], tix[r], b0, j0, b1, j1, b2, j2, b3, j3);
        }
    }

    if (lane < 4) {
        #pragma unroll
        for (int r = 0; r < 4; ++r)
            #pragma unroll
            for (int j = 0; j < 4; ++j) {
                cV[wav][lane * 4 + r][j] = tv[r][j];
                cI[wav][lane * 4 + r][j] = tix[r][j];
            }
    }
    __syncthreads();

    if (tid < 16) {
        float mv[4]; int mi[4];
        #pragma unroll
        for (int j = 0; j < 4; ++j) { mv[j] = cV[0][tid][j]; mi[j] = cI[0][tid][j]; }
        merge4(mv, mi,
               cV[1][tid][0], cI[1][tid][0],
               cV[1][tid][1], cI[1][tid][1],
               cV[1][tid][2], cI[1][tid][2],
               cV[1][tid][3], cI[1][tid][3]);
        const size_t row = (size_t)b * T_SEQ + tblk + tid;
        float4 vv = {mv[0], mv[1], mv[2], mv[3]};
        int4   ii = {mi[0], mi[1], mi[2], mi[3]};
        *reinterpret_cast<float4*>(candVal + ((size_t)half * NROWS + row) * 4) = vv;
        *reinterpret_cast<int4*>(candIdx + ((size_t)half * NROWS + row) * 4) = ii;
    }
}

// ---------- Phase 2b: merge halves + fused gather/mean (UNCHANGED) ----------
__global__ __launch_bounds__(256) void merge_gather(
    const float* __restrict__ x,
    const float* __restrict__ candVal, const int* __restrict__ candIdx,
    float* __restrict__ out)
{
    __shared__ int topIdx[8][4];

    const int tid  = threadIdx.x;
    const int row0 = blockIdx.x * 8;
    const int b    = row0 >> 11;

    if (tid < 8) {
        const size_t row = row0 + tid;
        float4 v0 = *reinterpret_cast<const float4*>(candVal + row * 4);
        int4   i0 = *reinterpret_cast<const int4*>(candIdx + row * 4);
        float4 v1 = *reinterpret_cast<const float4*>(candVal + ((size_t)NROWS + row) * 4);
        int4   i1 = *reinterpret_cast<const int4*>(candIdx + ((size_t)NROWS + row) * 4);
        float mv[4] = {v0.x, v0.y, v0.z, v0.w};
        int   mi[4] = {i0.x, i0.y, i0.z, i0.w};
        merge4(mv, mi, v1.x, i1.x, v1.y, i1.y, v1.z, i1.z, v1.w, i1.w);
        #pragma unroll
        for (int j = 0; j < 4; ++j) topIdx[tid][j] = mi[j];
    }
    __syncthreads();

    const float* xb = x + (size_t)b * T_SEQ * D_MODEL;
    float* ob = out + (size_t)row0 * D_MODEL;
    #pragma unroll
    for (int r = 0; r < 8; ++r) {
        const int i0 = topIdx[r][0], i1 = topIdx[r][1], i2 = topIdx[r][2], i3 = topIdx[r][3];
        float4 a0 = *(reinterpret_cast<const float4*>(xb + (size_t)i0 * D_MODEL) + tid);
        float4 a1 = *(reinterpret_cast<const float4*>(xb + (size_t)i1 * D_MODEL) + tid);
        float4 a2 = *(reinterpret_cast<const float4*>(xb + (size_t)i2 * D_MODEL) + tid);
        float4 a3 = *(reinterpret_cast<const float4*>(xb + (size_t)i3 * D_MODEL) + tid);
        float4 o;
        o.x = (a0.x + a1.x + a2.x + a3.x) * 0.25f;
        o.y = (a0.y + a1.y + a2.y + a3.y) * 0.25f;
        o.z = (a0.z + a1.z + a2.z + a3.z) * 0.25f;
        o.w = (a0.w + a1.w + a2.w + a3.w) * 0.25f;
        *(reinterpret_cast<float4*>(ob + (size_t)r * D_MODEL) + tid) = o;
    }
}

extern "C" void kernel_launch(void* const* d_in, const int* in_sizes, int n_in,
                              void* d_out, int out_size, void* d_ws, size_t ws_size,
                              hipStream_t stream) {
    const float* x  = (const float*)d_in[0];
    const float* Wq = (const float*)d_in[1];
    const float* bq = (const float*)d_in[2];
    const float* Wk = (const float*)d_in[3];
    const float* bk = (const float*)d_in[4];
    float* out = (float*)d_out;

    // ws layout: [tab 4KB][Wdt 512KB][Qt 1MB][Kt 1MB][candVal 128KB][candIdx 128KB]
    char* wsb = (char*)d_ws;
    int*    tab  = (int*)wsb;                                            // 4 KB reserved
    double* Wdt  = (double*)(wsb + 4096);                                // 512 KB
    float*  Qt   = (float*)(wsb + 4096 + (size_t)D_MODEL * NOUT * 8);    // 1 MB
    float*  Kt   = Qt + (size_t)NBATCH * 32 * T_SEQ;                     // 1 MB
    float*  candVal = (float*)((char*)Kt + (size_t)NBATCH * 32 * T_SEQ * 4);
    int*    candIdx = (int*)((char*)candVal + (size_t)2 * NROWS * 4 * 4);

    mfma_probe<<<dim3(1), dim3(64), 0, stream>>>(tab);
    wprep_kernel<<<dim3(256), dim3(256), 0, stream>>>(Wq, Wk, Wdt);
    proj_mfma<<<dim3(NROWS / 16), dim3(256), 0, stream>>>(x, Wdt, bq, bk, tab, Qt, Kt);
    sim_topk<<<dim3(1024), dim3(128), 0, stream>>>(Qt, Kt, candVal, candIdx);
    merge_gather<<<dim3(1024), dim3(256), 0, stream>>>(x, candVal, candIdx, out);
}

// Round 6
// 163.918 us; speedup vs baseline: 1.8283x; 1.0431x over previous
//
#include <hip/hip_runtime.h>
#include <math.h>

#define D_MODEL 1024
#define T_SEQ   2048
#define NBATCH  4
#define NROWS   (NBATCH * T_SEQ)          // 8192
#define NOUT    64                        // 32 q + 32 k
#define NQTR    4                         // s-quarters in sim

#define SKLD 264   // klds row stride (floats): 256 + 8, 16B aligned, <=2-way banks
#define SQLD 36    // qlds row stride (floats): 32 + 4
#define XLD  1032  // xlds row stride (floats): 1024 + 8, 16B aligned

typedef double v4df __attribute__((ext_vector_type(4)));

// ---------- top-4 helpers: total order = (value desc, index asc) ----------
__device__ __forceinline__ bool key_gt(float av, int ai, float bv, int bi) {
    return (av > bv) || (av == bv && ai < bi);
}

__device__ __forceinline__ void cmpswap(float& v0, int& i0, float& v1, int& i1) {
    bool sw = key_gt(v1, i1, v0, i0);
    float nv0 = sw ? v1 : v0, nv1 = sw ? v0 : v1;
    int   ni0 = sw ? i1 : i0, ni1 = sw ? i0 : i1;
    v0 = nv0; v1 = nv1; i0 = ni0; i1 = ni1;
}

// merge sorted-desc a[4] with sorted-desc b[4] -> top4 of union into a (bitonic)
__device__ __forceinline__ void merge4(float (&a)[4], int (&ai)[4],
                                       float b0, int j0, float b1, int j1,
                                       float b2, int j2, float b3, int j3) {
    if (!key_gt(a[0], ai[0], b3, j3)) { a[0] = b3; ai[0] = j3; }
    if (!key_gt(a[1], ai[1], b2, j2)) { a[1] = b2; ai[1] = j2; }
    if (!key_gt(a[2], ai[2], b1, j1)) { a[2] = b1; ai[2] = j1; }
    if (!key_gt(a[3], ai[3], b0, j0)) { a[3] = b0; ai[3] = j0; }
    cmpswap(a[0], ai[0], a[2], ai[2]);
    cmpswap(a[1], ai[1], a[3], ai[3]);
    cmpswap(a[0], ai[0], a[1], ai[1]);
    cmpswap(a[2], ai[2], a[3], ai[3]);
}

// insert candidate (v, idx) into sorted-desc top4; strict > keeps earlier index on ties
__device__ __forceinline__ void insert4(float (&tv)[4], int (&tix)[4], float v, int idx) {
    if (v > tv[3]) {
        bool g0 = v > tv[0], g1 = v > tv[1], g2 = v > tv[2];
        float n0 = g0 ? v : tv[0];
        int   m0 = g0 ? idx : tix[0];
        float n1 = g1 ? (g0 ? tv[0] : v) : tv[1];
        int   m1 = g1 ? (g0 ? tix[0] : idx) : tix[1];
        float n2 = g2 ? (g1 ? tv[1] : v) : tv[2];
        int   m2 = g2 ? (g1 ? tix[1] : idx) : tix[2];
        float n3 = g2 ? tv[2] : v;
        int   m3 = g2 ? tix[2] : idx;
        tv[0] = n0; tv[1] = n1; tv[2] = n2; tv[3] = n3;
        tix[0] = m0; tix[1] = m1; tix[2] = m2; tix[3] = m3;
    }
}

// ---------- Phase 0: probe the f64 MFMA fragment layout in-device ----------
// tab layout (ints): [0]=flag, [1..64]=am, [65..128]=ak, [129..192]=bk,
//                    [193..256]=bn, [257..512]=dm[lane][4], [513..768]=dn[lane][4]
__global__ __launch_bounds__(64) void mfma_probe(int* __restrict__ tab)
{
    __shared__ double Aref[16][4];
    __shared__ double Bref[4][16];
    __shared__ double Dref[16][16];

    const int lane = threadIdx.x;
    {
        const int m = lane & 15, k = lane >> 4;
        Aref[m][k] = (double)(1 + m * 4 + k);     // distinct, asymmetric
        Bref[k][m] = (double)(1 + k * 16 + m);
    }
    __syncthreads();
    for (int e = lane; e < 256; e += 64) {
        const int m = e >> 4, n = e & 15;
        double s = 0.0;
        for (int k = 0; k < 4; ++k) s += Aref[m][k] * Bref[k][n];
        Dref[m][n] = s;   // exact integer-valued f64
    }
    __syncthreads();

    int found = -1;
    for (int h = 0; h < 16; ++h) {
        if (found >= 0) break;
        const int fa = h & 1, fb = (h >> 1) & 1, fd = h >> 2;
        const int am = fa ? (lane >> 2) : (lane & 15);
        const int ak = fa ? (lane & 3)  : (lane >> 4);
        const int bn = fb ? (lane >> 2) : (lane & 15);
        const int bk = fb ? (lane & 3)  : (lane >> 4);
        v4df c = {0.0, 0.0, 0.0, 0.0};
        c = __builtin_amdgcn_mfma_f64_16x16x4f64(Aref[am][ak], Bref[bk][bn], c, 0, 0, 0);
        bool ok = true;
        #pragma unroll
        for (int i = 0; i < 4; ++i) {
            int dm, dn;
            if (fd == 0)      { dm = 4 * (lane >> 4) + i; dn = lane & 15; }
            else if (fd == 1) { dn = 4 * (lane >> 4) + i; dm = lane & 15; }
            else if (fd == 2) { dm = (lane >> 4) + 4 * i; dn = lane & 15; }
            else              { dn = (lane >> 4) + 4 * i; dm = lane & 15; }
            if (c[i] != Dref[dm][dn]) ok = false;
        }
        if (__all(ok)) found = h;
    }

    const int fa = (found >= 0) ? (found & 1) : 0;
    const int fb = (found >= 0) ? ((found >> 1) & 1) : 0;
    const int fd = (found >= 0) ? (found >> 2) : 0;
    tab[1   + lane] = fa ? (lane >> 2) : (lane & 15);
    tab[65  + lane] = fa ? (lane & 3)  : (lane >> 4);
    tab[129 + lane] = fb ? (lane & 3)  : (lane >> 4);
    tab[193 + lane] = fb ? (lane >> 2) : (lane & 15);
    #pragma unroll
    for (int i = 0; i < 4; ++i) {
        int dm, dn;
        if (fd == 0)      { dm = 4 * (lane >> 4) + i; dn = lane & 15; }
        else if (fd == 1) { dn = 4 * (lane >> 4) + i; dm = lane & 15; }
        else if (fd == 2) { dm = (lane >> 4) + 4 * i; dn = lane & 15; }
        else              { dn = (lane >> 4) + 4 * i; dm = lane & 15; }
        tab[257 + lane * 4 + i] = dm;
        tab[513 + lane * 4 + i] = dn;
    }
    if (lane == 0) tab[0] = found;
}

// ---------- Phase 1a: convert W to f64, transposed Wdt[d][64] ----------
__global__ __launch_bounds__(256) void wprep_kernel(
    const float* __restrict__ Wq, const float* __restrict__ Wk,
    double* __restrict__ Wdt)
{
    const int idx = blockIdx.x * 256 + threadIdx.x;   // 65536 total
    const int o = idx & 63;
    const int d = idx >> 6;
    float v = (o < 32) ? Wq[(size_t)o * D_MODEL + d]
                       : Wk[(size_t)(o - 32) * D_MODEL + d];
    Wdt[(size_t)d * 64 + o] = (double)v;
}

// ---------- Phase 1b: projection via f64 MFMA, d-split wave pairs ----------
// grid 512 (= 8192 rows / 16), block 512 (8 waves). Wave pair (og, half):
// og = wav>>1 owns out-tile og*16; half = wav&1 owns d in [half*512, half*512+512).
// x staged once (16 rows x 1024 d, 66 KB); f64 combine low+high fixed order.
// 2 blocks/CU -> 16 waves/CU; MFMA critical path 128 (vs 256 chained).
__global__ __launch_bounds__(512) void proj_mfma(
    const float* __restrict__ x, const double* __restrict__ Wdt,
    const float* __restrict__ bq, const float* __restrict__ bk_,
    const int* __restrict__ tab,
    float* __restrict__ Qt, float* __restrict__ Kt)
{
    __shared__ float  xlds[16 * XLD];     // 66048 B
    __shared__ double comb[4][64][4];     // 8192 B

    const int tid  = threadIdx.x;
    const int lane = tid & 63;
    const int wav  = tid >> 6;                                      // 0..7
    const int og   = __builtin_amdgcn_readfirstlane(wav >> 1);      // 0..3
    const int half = __builtin_amdgcn_readfirstlane(wav & 1);       // 0..1
    const int row0 = blockIdx.x * 16;
    const int dbase = half * 512;

    const int flag = tab[0];
    const int am  = tab[1   + lane];
    const int ak  = tab[65  + lane];
    const int bkk = tab[129 + lane];
    const int bn  = tab[193 + lane];

    const double* wcol = Wdt + og * 16;   // + d*64 + bn

    // stage x: 16 rows x 1024 d = 4096 float4, 8 per thread, coalesced
    #pragma unroll
    for (int j = 0; j < 8; ++j) {
        const int f  = j * 512 + tid;
        const int r  = f >> 8;            // 0..15
        const int c4 = f & 255;           // float4 within row
        float4 v = *reinterpret_cast<const float4*>(
            x + (size_t)(row0 + r) * D_MODEL + c4 * 4);
        *reinterpret_cast<float4*>(&xlds[r * XLD + c4 * 4]) = v;
    }
    __syncthreads();

    v4df acc = {0.0, 0.0, 0.0, 0.0};

    if (flag >= 0) {
        // 128 chained MFMAs over this half's 512 d (k ascending, deterministic)
        #pragma unroll 8
        for (int kk = 0; kk < 128; ++kk) {
            double a = (double)xlds[am * XLD + dbase + kk * 4 + ak];
            double b = wcol[(size_t)(dbase + kk * 4 + bkk) * 64 + bn];
            acc = __builtin_amdgcn_mfma_f64_16x16x4f64(a, b, acc, 0, 0, 0);
        }
    } else {
        // scalar f64 fallback: out n = lane&15, rows 4*(lane>>4)+i
        const int n  = lane & 15;
        const int r4 = (lane >> 4) * 4;
        for (int dd = 0; dd < 512; ++dd) {
            const int d = dbase + dd;
            double wv = wcol[(size_t)d * 64 + n];
            #pragma unroll
            for (int i = 0; i < 4; ++i)
                acc[i] = fma((double)xlds[(r4 + i) * XLD + d], wv, acc[i]);
        }
    }

    if (half == 1) {
        #pragma unroll
        for (int i = 0; i < 4; ++i) comb[og][lane][i] = acc[i];
    }
    __syncthreads();

    if (half == 0) {
        // total = low + high (fixed order -> deterministic), + bias, store
        #pragma unroll
        for (int i = 0; i < 4; ++i) {
            const double tot = acc[i] + comb[og][lane][i];
            const int dmv = tab[257 + lane * 4 + i];
            const int dnv = tab[513 + lane * 4 + i];
            const int out = og * 16 + dnv;
            const int row = row0 + dmv;
            const int bb  = row >> 11, t = row & 2047;
            const double bias = (out < 32) ? (double)bq[out] : (double)bk_[out - 32];
            const float v = (float)(tot + bias);
            if (out < 32) Qt[((size_t)bb * 32 + out) * T_SEQ + t] = v;
            else          Kt[((size_t)bb * 32 + (out - 32)) * T_SEQ + t] = v;
        }
    }
}

// ---------- Phase 2a: sim over an s-quarter, per-row top-4 -> ws ----------
// grid 1024 = b(4) x ttile(64) x quarter(4); block 256 (4 waves)
// tile: 32 t-rows x 512 s (2 stages of 256). micro-tile 4t x 8s.
// LDS ~38.4 KB -> 4 blocks/CU = 16 waves/CU.
__global__ __launch_bounds__(256) void sim_topk(
    const float* __restrict__ Qt, const float* __restrict__ Kt,
    float* __restrict__ candVal /* [NQTR][NROWS][4] */,
    int*   __restrict__ candIdx /* [NQTR][NROWS][4] */)
{
    __shared__ float klds[32 * SKLD];     // 33792 B
    __shared__ float qlds[32 * SQLD];     // 4608 B
    __shared__ float cV[4][32][4];
    __shared__ int   cI[4][32][4];

    const int tid  = threadIdx.x;
    const int lane = tid & 63;
    const int wav  = tid >> 6;            // 0..3
    const int qtr  = blockIdx.x & 3;
    const int tt   = (blockIdx.x >> 2) & 63;
    const int b    = blockIdx.x >> 8;
    const int tblk = tt * 32;
    const int sq0  = qtr * 512;

    const float* QtB = Qt + (size_t)b * 32 * T_SEQ;
    const float* KtB = Kt + (size_t)b * 32 * T_SEQ;

    // stage Q^T tile: 32 i x 32 t (exactly 256 float4s)
    {
        const int i  = tid >> 3;
        const int t4 = (tid & 7) * 4;
        float4 v = *reinterpret_cast<const float4*>(QtB + (size_t)i * T_SEQ + tblk + t4);
        *reinterpret_cast<float4*>(&qlds[i * SQLD + t4]) = v;
    }

    const int t0 = (tid & 7) * 4;         // 8 t-groups x 4 rows
    const int s0 = (tid >> 3) * 8;        // 32 s-groups x 8

    float tv[4][4]; int tix[4][4];
    #pragma unroll
    for (int r = 0; r < 4; ++r)
        #pragma unroll
        for (int j = 0; j < 4; ++j) { tv[r][j] = -INFINITY; tix[r][j] = 0x7fffffff; }

    for (int st = 0; st < 2; ++st) {
        __syncthreads();   // covers qlds at st==0, prev klds consumption after
        // stage K^T tile: 32 i x 256 s (2048 float4s, 8/thread), coalesced
        #pragma unroll
        for (int j = 0; j < 8; ++j) {
            const int f  = (tid + j * 256) * 4;
            const int ki = f >> 8;
            const int ks = f & 255;
            float4 v = *reinterpret_cast<const float4*>(
                KtB + (size_t)ki * T_SEQ + sq0 + st * 256 + ks);
            *reinterpret_cast<float4*>(&klds[ki * SKLD + ks]) = v;
        }
        __syncthreads();

        float acc[4][8];
        #pragma unroll
        for (int r = 0; r < 4; ++r)
            #pragma unroll
            for (int c = 0; c < 8; ++c) acc[r][c] = 0.f;

        #pragma unroll 4
        for (int i = 0; i < 32; ++i) {
            float4 qv  = *reinterpret_cast<const float4*>(&qlds[i * SQLD + t0]);
            float4 kv0 = *reinterpret_cast<const float4*>(&klds[i * SKLD + s0]);
            float4 kv1 = *reinterpret_cast<const float4*>(&klds[i * SKLD + s0 + 4]);
            const float qa[4] = {qv.x, qv.y, qv.z, qv.w};
            const float ka[8] = {kv0.x, kv0.y, kv0.z, kv0.w, kv1.x, kv1.y, kv1.z, kv1.w};
            #pragma unroll
            for (int r = 0; r < 4; ++r)
                #pragma unroll
                for (int c = 0; c < 8; ++c)
                    acc[r][c] = fmaf(qa[r], ka[c], acc[r][c]);
        }

        const int sbase = sq0 + st * 256 + s0;
        #pragma unroll
        for (int c = 0; c < 8; ++c)
            #pragma unroll
            for (int r = 0; r < 4; ++r)
                insert4(tv[r], tix[r], acc[r][c], sbase + c);
    }

    // wave butterfly: masks 8..32 preserve t-group (lane&7)
    #pragma unroll
    for (int m = 8; m <= 32; m <<= 1) {
        #pragma unroll
        for (int r = 0; r < 4; ++r) {
            float b0 = __shfl_xor(tv[r][0], m, 64);
            float b1 = __shfl_xor(tv[r][1], m, 64);
            float b2 = __shfl_xor(tv[r][2], m, 64);
            float b3 = __shfl_xor(tv[r][3], m, 64);
            int   j0 = __shfl_xor(tix[r][0], m, 64);
            int   j1 = __shfl_xor(tix[r][1], m, 64);
            int   j2 = __shfl_xor(tix[r][2], m, 64);
            int   j3 = __shfl_xor(tix[r][3], m, 64);
            merge4(tv[r], tix[r], b0, j0, b1, j1, b2, j2, b3, j3);
        }
    }

    if (lane < 8) {
        #pragma unroll
        for (int r = 0; r < 4; ++r)
            #pragma unroll
            for (int j = 0; j < 4; ++j) {
                cV[wav][lane * 4 + r][j] = tv[r][j];
                cI[wav][lane * 4 + r][j] = tix[r][j];
            }
    }
    __syncthreads();

    // cross-wave merge (4 waves), write per-quarter candidate lists
    if (tid < 32) {
        float mv[4]; int mi[4];
        #pragma unroll
        for (int j = 0; j < 4; ++j) { mv[j] = cV[0][tid][j]; mi[j] = cI[0][tid][j]; }
        #pragma unroll
        for (int w = 1; w < 4; ++w)
            merge4(mv, mi,
                   cV[w][tid][0], cI[w][tid][0],
                   cV[w][tid][1], cI[w][tid][1],
                   cV[w][tid][2], cI[w][tid][2],
                   cV[w][tid][3], cI[w][tid][3]);
        const size_t row = (size_t)b * T_SEQ + tblk + tid;
        float4 vv = {mv[0], mv[1], mv[2], mv[3]};
        int4   ii = {mi[0], mi[1], mi[2], mi[3]};
        *reinterpret_cast<float4*>(candVal + ((size_t)qtr * NROWS + row) * 4) = vv;
        *reinterpret_cast<int4*>(candIdx + ((size_t)qtr * NROWS + row) * 4) = ii;
    }
}

// ---------- Phase 2b: merge quarters + fused gather/mean ----------
// grid 1024 (8 rows/block), block 256 thr
__global__ __launch_bounds__(256) void merge_gather(
    const float* __restrict__ x,
    const float* __restrict__ candVal, const int* __restrict__ candIdx,
    float* __restrict__ out)
{
    __shared__ int topIdx[8][4];

    const int tid  = threadIdx.x;
    const int row0 = blockIdx.x * 8;
    const int b    = row0 >> 11;

    if (tid < 8) {
        const size_t row = row0 + tid;
        float4 v0 = *reinterpret_cast<const float4*>(candVal + row * 4);
        int4   i0 = *reinterpret_cast<const int4*>(candIdx + row * 4);
        float mv[4] = {v0.x, v0.y, v0.z, v0.w};
        int   mi[4] = {i0.x, i0.y, i0.z, i0.w};
        #pragma unroll
        for (int q = 1; q < NQTR; ++q) {
            float4 v1 = *reinterpret_cast<const float4*>(candVal + ((size_t)q * NROWS + row) * 4);
            int4   i1 = *reinterpret_cast<const int4*>(candIdx + ((size_t)q * NROWS + row) * 4);
            merge4(mv, mi, v1.x, i1.x, v1.y, i1.y, v1.z, i1.z, v1.w, i1.w);
        }
        #pragma unroll
        for (int j = 0; j < 4; ++j) topIdx[tid][j] = mi[j];
    }
    __syncthreads();

    const float* xb = x + (size_t)b * T_SEQ * D_MODEL;
    float* ob = out + (size_t)row0 * D_MODEL;
    #pragma unroll
    for (int r = 0; r < 8; ++r) {
        const int i0 = topIdx[r][0], i1 = topIdx[r][1], i2 = topIdx[r][2], i3 = topIdx[r][3];
        float4 a0 = *(reinterpret_cast<const float4*>(xb + (size_t)i0 * D_MODEL) + tid);
        float4 a1 = *(reinterpret_cast<const float4*>(xb + (size_t)i1 * D_MODEL) + tid);
        float4 a2 = *(reinterpret_cast<const float4*>(xb + (size_t)i2 * D_MODEL) + tid);
        float4 a3 = *(reinterpret_cast<const float4*>(xb + (size_t)i3 * D_MODEL) + tid);
        float4 o;
        o.x = (a0.x + a1.x + a2.x + a3.x) * 0.25f;
        o.y = (a0.y + a1.y + a2.y + a3.y) * 0.25f;
        o.z = (a0.z + a1.z + a2.z + a3.z) * 0.25f;
        o.w = (a0.w + a1.w + a2.w + a3.w) * 0.25f;
        *(reinterpret_cast<float4*>(ob + (size_t)r * D_MODEL) + tid) = o;
    }
}

extern "C" void kernel_launch(void* const* d_in, const int* in_sizes, int n_in,
                              void* d_out, int out_size, void* d_ws, size_t ws_size,
                              hipStream_t stream) {
    const float* x  = (const float*)d_in[0];
    const float* Wq = (const float*)d_in[1];
    const float* bq = (const float*)d_in[2];
    const float* Wk = (const float*)d_in[3];
    const float* bk = (const float*)d_in[4];
    float* out = (float*)d_out;

    // ws layout: [tab 4KB][Wdt 512KB][Qt 1MB][Kt 1MB][candVal 512KB][candIdx 512KB]
    char* wsb = (char*)d_ws;
    int*    tab  = (int*)wsb;                                            // 4 KB reserved
    double* Wdt  = (double*)(wsb + 4096);                                // 512 KB
    float*  Qt   = (float*)(wsb + 4096 + (size_t)D_MODEL * NOUT * 8);    // 1 MB
    float*  Kt   = Qt + (size_t)NBATCH * 32 * T_SEQ;                     // 1 MB
    float*  candVal = (float*)((char*)Kt + (size_t)NBATCH * 32 * T_SEQ * 4);
    int*    candIdx = (int*)((char*)candVal + (size_t)NQTR * NROWS * 4 * 4);

    mfma_probe<<<dim3(1), dim3(64), 0, stream>>>(tab);
    wprep_kernel<<<dim3(256), dim3(256), 0, stream>>>(Wq, Wk, Wdt);
    proj_mfma<<<dim3(NROWS / 16), dim3(512), 0, stream>>>(x, Wdt, bq, bk, tab, Qt, Kt);
    sim_topk<<<dim3(1024), dim3(256), 0, stream>>>(Qt, Kt, candVal, candIdx);
    merge_gather<<<dim3(1024), dim3(256), 0, stream>>>(x, candVal, candIdx, out);
}